// Round 5
// baseline (277.582 us; speedup 1.0000x reference)
//
#include <hip/hip_runtime.h>

#define TSTEPS 365
#define BGRID  20000
#define NMUL   4
#define NEARZERO 1e-6f
#define C    8              // steps per chunk
#define NCH  (TSTEPS / C)   // 45 full chunks
#define TAIL (TSTEPS - NCH * C)  // 5

struct F3 { float p, t, pet; };   // 12B, innermost (.,3) layout

// Two HBV chains per thread as TWO INDEPENDENT SCALAR streams (struct of two
// floats, per-member ops). Round 3 proved this does NOT SLP-vectorize -> each
// chain is a separate scalar dep-chain and the scheduler interleaves them to
// fill dependency stalls (round 1 evidence). Round 4 proved pk-packing the
// chains REMOVES that ILP and regresses 30%.
struct alignas(8) f2 { float x, y; };
__device__ __forceinline__ f2 operator+(f2 a, f2 b) { return {a.x + b.x, a.y + b.y}; }
__device__ __forceinline__ f2 operator-(f2 a, f2 b) { return {a.x - b.x, a.y - b.y}; }
__device__ __forceinline__ f2 operator*(f2 a, f2 b) { return {a.x * b.x, a.y * b.y}; }
__device__ __forceinline__ f2 f2min (f2 a, f2 b)   { return {fminf(a.x,b.x), fminf(a.y,b.y)}; }
__device__ __forceinline__ f2 f2max0(f2 a)         { return {fmaxf(a.x,0.f), fmaxf(a.y,0.f)}; }
__device__ __forceinline__ f2 f2maxs(f2 a, float s){ return {fmaxf(a.x,s), fmaxf(a.y,s)}; }

// lanes 2i/2i+1 share b. quad_perm(1,0,3,2) swaps pair partners (0<->1, 2<->3).
__device__ __forceinline__ float pair_swap(float x) {
    int a = __builtin_amdgcn_update_dpp(0, __float_as_int(x),
                                        0xB1 /*quad_perm(1,0,3,2)*/, 0xF, 0xF, true);
    return __int_as_float(a);
}

// raw transcendentals: bare v_log_f32 / v_exp_f32 (domain: log in >= 1e-6,
// exp2 in [-120, 0] — all normal, no guard codegen).
__device__ __forceinline__ float fast_log2(float x) { return __builtin_amdgcn_logf(x); }
__device__ __forceinline__ float fast_exp2(float x) { return __builtin_amdgcn_exp2f(x); }
// pow(x,e) clamped to <=1, per half (trans units are scalar-only)
__device__ __forceinline__ f2 f2pow1(f2 xv, f2 e) {
    f2 l = { fast_log2(xv.x), fast_log2(xv.y) };
    f2 m = e * l;
    return { fminf(fast_exp2(m.x), 1.0f), fminf(fast_exp2(m.y), 1.0f) };
}
// clamp(v, lo, hi) in one v_med3_f32 per half
__device__ __forceinline__ f2 f2clamp(f2 a, float lo, float hi) {
    return { __builtin_amdgcn_fmed3f(a.x, lo, hi),
             __builtin_amdgcn_fmed3f(a.y, lo, hi) };
}

__device__ __forceinline__ f2 ld2(const float* p, int i) {
    f2 r; r.x = p[i]; r.y = p[i + 1]; return r;      // i even -> dwordx2
}

// Phase-separated chunk pipeline (round 2 structure, kept):
//   LOAD(next chunk) ; STORE(prev chunk results) ; COMPUTE(current chunk)
#define LOAD_CHUNK(BUF, N)                                                  \
    _Pragma("unroll")                                                       \
    for (int j_ = 0; j_ < (N); ++j_) { BUF[j_] = *fp; fp += BGRID; }

#define STORE_CHUNK(QS, N)                                                  \
    _Pragma("unroll")                                                       \
    for (int j_ = 0; j_ < (N); ++j_) {                                      \
        *qf = QS[j_]; qf += BGRID * 2;    /* one dwordx2: adjacent k pair */ \
        const float h_ = QS[j_].x + QS[j_].y;                               \
        *qa = (h_ + pair_swap(h_)) * 0.25f; qa += BGRID;                    \
    }

#define COMPUTE_CHUNK(BUF, QO, N)                                           \
    _Pragma("unroll")                                                       \
    for (int j_ = 0; j_ < (N); ++j_) { step(BUF[j_], QO[j_]); }

// thread = b*2 + khalf; cells ADJACENT: k = 2*khalf + {0,1} (c0 = tid*2)
// -> q-store is one 8B dwordx2, params load as dwordx2.
__global__ __launch_bounds__(64) __attribute__((amdgpu_waves_per_eu(1, 2)))
void hbv_fwd(
    const float* __restrict__ forcing,   // (T, B, 3)
    const float* __restrict__ pBETA,  const float* __restrict__ pFC,
    const float* __restrict__ pK0,    const float* __restrict__ pK1,
    const float* __restrict__ pK2,    const float* __restrict__ pLP,
    const float* __restrict__ pPERC,  const float* __restrict__ pUZL,
    const float* __restrict__ pTT,    const float* __restrict__ pCFMAX,
    const float* __restrict__ pCFR,   const float* __restrict__ pCWH,
    const float* __restrict__ pBETAET,const float* __restrict__ pC,
    float* __restrict__ out_avg,         // (T, B)
    float* __restrict__ out_q)           // (T, B, NMUL)
{
    const int tid = blockIdx.x * 64 + threadIdx.x;   // grid exact: 625*64 = 40000
    const int b  = tid >> 1;
    const int c0 = tid * 2;                          // = b*4 + 2*khalf

    const f2 parBETA   = ld2(pBETA, c0);
    const f2 parFC     = ld2(pFC, c0);
    const f2 parK0     = ld2(pK0, c0);
    const f2 parK1     = ld2(pK1, c0);
    const f2 parK2     = ld2(pK2, c0);
    const f2 parLP     = ld2(pLP, c0);
    const f2 parPERC   = ld2(pPERC, c0);
    const f2 parUZL    = ld2(pUZL, c0);
    const f2 parTT     = ld2(pTT, c0);
    const f2 parCFMAX  = ld2(pCFMAX, c0);
    const f2 parCFR    = ld2(pCFR, c0);
    const f2 parCWH    = ld2(pCWH, c0);
    const f2 parBETAET = ld2(pBETAET, c0);
    const f2 parC      = ld2(pC, c0);

    const f2 refreeze_coef = parCFR * parCFMAX;
    f2 inv_FC, inv_LPFC;
    inv_FC.x   = 1.0f / parFC.x;                 inv_FC.y   = 1.0f / parFC.y;
    inv_LPFC.x = 1.0f / (parLP.x * parFC.x);     inv_LPFC.y = 1.0f / (parLP.y * parFC.y);

    f2 snow = {NEARZERO, NEARZERO}, melt = {0.f,0.f}, sm = {0.f,0.f},
       suz = {0.f,0.f}, slz = {0.f,0.f};

    // walked 64-bit pointers, shared by both chains
    const F3* __restrict__ fp = (const F3*)forcing + b;     // stride BGRID per t
    f2* __restrict__ qf = (f2*)(out_q + c0);                 // stride BGRID*2 f2 per t
    float* __restrict__ qa = out_avg + b;                    // stride BGRID

    auto step = [&](const F3 fv, f2 &qo) {
        // ---- snow module ----
        f2 td; td.x = fv.t - parTT.x; td.y = fv.t - parTT.y;
        f2 rain; rain.x = td.x > 0.f ? fv.p : 0.f;
                 rain.y = td.y > 0.f ? fv.p : 0.f;
        f2 snow_in; snow_in.x = fv.p - rain.x; snow_in.y = fv.p - rain.y;
        f2 snow1 = snow + snow_in;
        const f2 pot_melt = parCFMAX * f2max0(td);
        const f2 melt_amt = f2min(pot_melt, snow1);
        snow1 = snow1 - melt_amt;
        f2 melt1 = melt + melt_amt;
        f2 pot_rfz; pot_rfz.x = refreeze_coef.x * fmaxf(-td.x, 0.f);
                    pot_rfz.y = refreeze_coef.y * fmaxf(-td.y, 0.f);
        const f2 rfz = f2min(pot_rfz, melt1);
        snow = snow1 + rfz;
        melt1 = melt1 - rfz;
        // tosoil = max(melt1 - CWH*snow, 0): fma + max
        f2 tosoil; tosoil.x = fmaxf(fmaf(-parCWH.x, snow.x, melt1.x), 0.f);
                   tosoil.y = fmaxf(fmaf(-parCWH.y, snow.y, melt1.y), 0.f);
        melt = melt1 - tosoil;

        // ---- soil module ----
        f2 x1; x1.x = fmaxf(sm.x * inv_FC.x, NEARZERO);
               x1.y = fmaxf(sm.y * inv_FC.y, NEARZERO);
        const f2 soil_wet = f2pow1(x1, parBETA);
        const f2 rt = rain + tosoil;
        const f2 recharge = rt * soil_wet;
        const f2 sm1 = (sm + rt) - recharge;
        const f2 sm2 = f2min(sm1, parFC);        // == sm1 - excess (1 op on path)
        const f2 excess = sm1 - sm2;             // off-path, feeds suz
        f2 x2; x2.x = __builtin_amdgcn_fmed3f(sm2.x * inv_LPFC.x, NEARZERO, 1.0f);
               x2.y = __builtin_amdgcn_fmed3f(sm2.y * inv_LPFC.y, NEARZERO, 1.0f);
        const f2 ef = f2pow1(x2, parBETAET);
        // sm_ae = max(sm2 - pet*ef, eps)  (etact = min(pet*ef, sm2) eliminated)
        f2 sm_ae; sm_ae.x = fmaxf(fmaf(-fv.pet, ef.x, sm2.x), NEARZERO);
                  sm_ae.y = fmaxf(fmaf(-fv.pet, ef.y, sm2.y), NEARZERO);
        // omr = 1 - min(sm_ae/FC, 1) = max(1 - sm_ae*invFC, 0): fma + max
        f2 omr; omr.x = fmaxf(fmaf(-inv_FC.x, sm_ae.x, 1.0f), 0.f);
                omr.y = fmaxf(fmaf(-inv_FC.y, sm_ae.y, 1.0f), 0.f);
        const f2 cslz = parC * slz;              // prev-step slz: fully off-path
        f2 cap; cap.x = fminf(slz.x, cslz.x * omr.x);
                cap.y = fminf(slz.y, cslz.y * omr.y);
        sm = f2maxs(sm_ae + cap, NEARZERO);
        const f2 slz_ac = f2maxs(slz - cap, NEARZERO);

        // ---- response routine ----
        const f2 suz1 = (suz + recharge) + excess;
        const f2 suz2 = f2max0(suz1 - parPERC);  // suz1 - perc (2 ops on path)
        const f2 perc = suz1 - suz2;             // off-path, feeds slz
        const f2 slz1 = slz_ac + perc;
        f2 q0; q0.x = parK0.x * fmaxf(suz2.x - parUZL.x, 0.f);
               q0.y = parK0.y * fmaxf(suz2.y - parUZL.y, 0.f);
        const f2 suz3 = suz2 - q0;
        const f2 q1 = parK1 * suz3;
        // suz = suz3 - K1*suz3 in one fused op; same for slz
        suz.x = fmaf(-parK1.x, suz3.x, suz3.x);
        suz.y = fmaf(-parK1.y, suz3.y, suz3.y);
        const f2 q2 = parK2 * slz1;
        slz.x = fmaf(-parK2.x, slz1.x, slz1.x);
        slz.y = fmaf(-parK2.y, slz1.y, slz1.y);
        qo = (q0 + q1) + q2;
    };

    // ---- software pipeline over 45 full chunks + 5-step tail ----------------
    F3 fA[C], fB[C];
    f2 qA[C], qB[C];

    LOAD_CHUNK(fA, C);                 // ch0 -> fA
    LOAD_CHUNK(fB, C);                 // ch1
    COMPUTE_CHUNK(fA, qA, C);          // ch0

    // chunks as A/B pairs (static buffer parity -> no runtime indexing)
#pragma clang loop unroll(disable)
    for (int p = 0; p < 21; ++p) {
        LOAD_CHUNK(fA, C);             // ch 2p+2
        STORE_CHUNK(qA, C);            // results of ch 2p
        COMPUTE_CHUNK(fB, qB, C);      // ch 2p+1
        LOAD_CHUNK(fB, C);             // ch 2p+3
        STORE_CHUNK(qB, C);            // results of ch 2p+1
        COMPUTE_CHUNK(fA, qA, C);      // ch 2p+2
    }
    // here: qA = ch42, fB = ch43; stored through ch41
    LOAD_CHUNK(fA, C);                 // ch44
    STORE_CHUNK(qA, C);                // ch42
    COMPUTE_CHUNK(fB, qB, C);          // ch43
    LOAD_CHUNK(fB, TAIL);              // ch45 (5 steps: t=360..364)
    STORE_CHUNK(qB, C);                // ch43
    COMPUTE_CHUNK(fA, qA, C);          // ch44
    STORE_CHUNK(qA, C);                // ch44
    COMPUTE_CHUNK(fB, qB, TAIL);       // ch45
    STORE_CHUNK(qB, TAIL);             // ch45 (s_endpgm drains)
}

extern "C" void kernel_launch(void* const* d_in, const int* in_sizes, int n_in,
                              void* d_out, int out_size, void* d_ws, size_t ws_size,
                              hipStream_t stream) {
    // inputs (fp32): 0 forcing, 1 parBETA, 2 parFC, 3 parK0, 4 parK1, 5 parK2,
    // 6 parLP, 7 parPERC, 8 parUZL, 9 parTT, 10 parCFMAX, 11 parCFR, 12 parCWH,
    // 13 parBETAET, 14 parC
    const float* forcing = (const float*)d_in[0];

    float* out_avg = (float*)d_out;                          // (T, B)
    float* out_q   = out_avg + (size_t)TSTEPS * BGRID;       // (T, B, NMUL)

    const int total = BGRID * NMUL / 2;  // 40000 threads, 2 adjacent cells each
    const int block = 64;                // single-wave workgroups
    const int grid  = total / block;     // exact: 625
    hbv_fwd<<<grid, block, 0, stream>>>(forcing,
        (const float*)d_in[1], (const float*)d_in[2], (const float*)d_in[3],
        (const float*)d_in[4], (const float*)d_in[5], (const float*)d_in[6],
        (const float*)d_in[7], (const float*)d_in[8], (const float*)d_in[9],
        (const float*)d_in[10], (const float*)d_in[11], (const float*)d_in[12],
        (const float*)d_in[13], (const float*)d_in[14],
        out_avg, out_q);
}